// Round 9
// baseline (208.731 us; speedup 1.0000x reference)
//
#include <hip/hip_runtime.h>
#include <hip/hip_bf16.h>

typedef __bf16 bf16x8 __attribute__((ext_vector_type(8)));
typedef __bf16 bf16x4 __attribute__((ext_vector_type(4)));
typedef float  floatx4 __attribute__((ext_vector_type(4)));

// B=2, C=128, N=4096. fp32 in/out.
// ws: qT[b][n][c] | kT[b][m][c] | vT2[b][c][m] (bf16, 2MB ea)
//     | Opart[s][b][n][c] bf16 | ml[s][b][n][2] f32 | cnt[64] int
// Softmax in raw-logit domain; 1.3*log2(e) folded into exp2 args via FMA.
// Cross-split merge fused into flash: last-arriving block per (b,n-tile) merges.

#define QSCALE 1.8755035f   // 1.3 * log2(e)

// ---------------- proj: MFMA QKV, W AND x hi/lo split (3-term) ----------------
// grid (N/32, 3, B), block 128 = 2 waves; wave owns 16 n.  (known-good, R7)
__global__ __launch_bounds__(128) void proj_kernel(
    const float* __restrict__ x,
    const float* __restrict__ Wq, const float* __restrict__ bq,
    const float* __restrict__ Wk, const float* __restrict__ bk,
    const float* __restrict__ Wv, const float* __restrict__ bv,
    __bf16* __restrict__ qT, __bf16* __restrict__ kT, __bf16* __restrict__ vT2)
{
    constexpr int C = 128, N = 4096;
    const int b = blockIdx.z, which = blockIdx.y, n0 = blockIdx.x * 32;
    const int tid = threadIdx.x;
    const int wv = tid >> 6, lane = tid & 63, l15 = lane & 15, quad = lane >> 4;
    const float* W    = (which == 0) ? Wq : (which == 1) ? Wk : Wv;
    const float* bias = (which == 0) ? bq : (which == 1) ? bk : bv;

    __shared__ __bf16 xhi[32][136];
    __shared__ __bf16 xlo[32][136];
    __shared__ __bf16 v_lds[128][40];

    #pragma unroll
    for (int rep = 0; rep < 8; ++rep) {
        const int j = tid + rep * 128;
        const int c = j >> 3, nl4 = (j & 7) * 4;
        const float4 xv = *(const float4*)(x + (size_t)(b * C + c) * N + n0 + nl4);
        #pragma unroll
        for (int r = 0; r < 4; ++r) {
            const float v = (&xv.x)[r];
            const __bf16 h = (__bf16)v;
            xhi[nl4 + r][c] = h;
            xlo[nl4 + r][c] = (__bf16)(v - (float)h);
        }
    }
    __syncthreads();

    bf16x8 xbh[4], xbl[4];
    #pragma unroll
    for (int kk = 0; kk < 4; ++kk) {
        xbh[kk] = *(bf16x8*)(&xhi[wv * 16 + l15][kk * 32 + quad * 8]);
        xbl[kk] = *(bf16x8*)(&xlo[wv * 16 + l15][kk * 32 + quad * 8]);
    }

    floatx4 acc[8];
    const floatx4 fz = {0.f, 0.f, 0.f, 0.f};
    #pragma unroll
    for (int t = 0; t < 8; ++t) acc[t] = fz;

    #pragma unroll
    for (int kk = 0; kk < 4; ++kk)
        #pragma unroll
        for (int ct = 0; ct < 8; ++ct) {
            const float* wp = W + (size_t)(ct * 16 + l15) * C + kk * 32 + quad * 8;
            const float4 w0 = *(const float4*)wp;
            const float4 w1 = *(const float4*)(wp + 4);
            bf16x8 ahi, alo;
            #pragma unroll
            for (int r = 0; r < 4; ++r) {
                const float v0 = (&w0.x)[r]; const __bf16 h0 = (__bf16)v0;
                ahi[r] = h0; alo[r] = (__bf16)(v0 - (float)h0);
                const float v1 = (&w1.x)[r]; const __bf16 h1 = (__bf16)v1;
                ahi[4 + r] = h1; alo[4 + r] = (__bf16)(v1 - (float)h1);
            }
            acc[ct] = __builtin_amdgcn_mfma_f32_16x16x32_bf16(ahi, xbh[kk], acc[ct], 0, 0, 0);
            acc[ct] = __builtin_amdgcn_mfma_f32_16x16x32_bf16(alo, xbh[kk], acc[ct], 0, 0, 0);
            acc[ct] = __builtin_amdgcn_mfma_f32_16x16x32_bf16(ahi, xbl[kk], acc[ct], 0, 0, 0);
        }

    const int n = n0 + wv * 16 + l15;
    if (which < 2) {
        __bf16* dst = (which == 0) ? qT : kT;
        #pragma unroll
        for (int ct = 0; ct < 8; ++ct) {
            const float4 b4 = *(const float4*)(bias + ct * 16 + quad * 4);
            bf16x4 o;
            #pragma unroll
            for (int r = 0; r < 4; ++r) o[r] = (__bf16)(acc[ct][r] + (&b4.x)[r]);
            *(bf16x4*)(dst + (size_t)(b * N + n) * C + ct * 16 + quad * 4) = o;
        }
    } else {
        #pragma unroll
        for (int ct = 0; ct < 8; ++ct) {
            const float4 b4 = *(const float4*)(bias + ct * 16 + quad * 4);
            #pragma unroll
            for (int r = 0; r < 4; ++r)
                v_lds[ct * 16 + quad * 4 + r][wv * 16 + l15] = (__bf16)(acc[ct][r] + (&b4.x)[r]);
        }
        __syncthreads();
        #pragma unroll
        for (int rep = 0; rep < 4; ++rep) {
            const int j = tid + rep * 128;
            const int c = j >> 2, m8 = (j & 3) * 8;
            *(bf16x8*)(vT2 + (size_t)(b * C + c) * N + n0 + m8) = *(bf16x8*)(&v_lds[c][m8]);
        }
    }
}

// ---------------- flash: 128-n tiles, wave owns 32 n, fused split-merge ----------------
// block 256 = 4 waves. grid flat 32*NSPLIT*B, XCD-pinned on batch via bid&7.
template <int NSPLIT, bool PARTIAL>
__global__ __launch_bounds__(256, 2) void flash_kernel(
    const __bf16* __restrict__ qT, const __bf16* __restrict__ kT,
    const __bf16* __restrict__ vT2, const float* __restrict__ x,
    const float* __restrict__ gamma_p, __bf16* __restrict__ Opart,
    float* __restrict__ ml, int* __restrict__ cnt, float* __restrict__ out)
{
    constexpr int C = 128, N = 4096, Bn = 2;
    const int bid = blockIdx.x;
    const int r7 = bid & 7;
    const int b = r7 >> 2;                         // XCD-pinned batch
    const int rest = (bid >> 3) * 4 + (r7 & 3);    // 0 .. 32*NSPLIT-1
    const int nt = rest / NSPLIT, split = rest % NSPLIT;
    const int n0 = nt * 128;
    const int tid = threadIdx.x;
    const int wv = tid >> 6, lane = tid & 63, l15 = lane & 15, quad = lane >> 4;

    __shared__ __bf16 k_s[64][136];
    __shared__ __bf16 v_s[128][72];
    __shared__ __bf16 p_s[4][32][72];
    __shared__ float cf[PARTIAL ? NSPLIT : 1][32]; // merge coefficients
    __shared__ float ot[32][132];                  // merge transpose buffer
    __shared__ int s_old;

    const int nA = n0 + wv * 32 + l15;             // col set A; B = +16
    bf16x8 qbA[4], qbB[4];
    #pragma unroll
    for (int kk = 0; kk < 4; ++kk) {
        qbA[kk] = *(const bf16x8*)(qT + (size_t)(b * N + nA) * C + kk * 32 + quad * 8);
        qbB[kk] = *(const bf16x8*)(qT + (size_t)(b * N + nA + 16) * C + kk * 32 + quad * 8);
    }

    float mA = -3.0e38f, lA = 0.f, mB = -3.0e38f, lB = 0.f;  // m in RAW logit domain
    floatx4 OA[8], OB[8];
    const floatx4 fz = {0.f, 0.f, 0.f, 0.f};
    #pragma unroll
    for (int t = 0; t < 8; ++t) { OA[t] = fz; OB[t] = fz; }

    const __bf16* kB = kT  + (size_t)b * N * C;
    const __bf16* vB = vT2 + (size_t)b * C * N;
    constexpr int ITERS = (N / NSPLIT) / 64;
    const int mbeg = split * (N / NSPLIT);

    bf16x8 kpre[4], vpre[4];
    #pragma unroll
    for (int rep = 0; rep < 4; ++rep) {
        const int kj = tid + rep * 256;
        kpre[rep] = *(const bf16x8*)(kB + (size_t)(mbeg + (kj >> 4)) * C + (kj & 15) * 8);
        const int vj = tid + rep * 256;
        vpre[rep] = *(const bf16x8*)(vB + (size_t)(vj >> 3) * N + mbeg + (vj & 7) * 8);
    }

    for (int it = 0; it < ITERS; ++it) {
        __syncthreads();
        #pragma unroll
        for (int rep = 0; rep < 4; ++rep) {
            const int kj = tid + rep * 256;
            *(bf16x8*)(&k_s[kj >> 4][(kj & 15) * 8]) = kpre[rep];
            const int vj = tid + rep * 256;
            *(bf16x8*)(&v_s[vj >> 3][(vj & 7) * 8]) = vpre[rep];
        }
        __syncthreads();

        if (it + 1 < ITERS) {
            const int m1 = mbeg + (it + 1) * 64;
            #pragma unroll
            for (int rep = 0; rep < 4; ++rep) {
                const int kj = tid + rep * 256;
                kpre[rep] = *(const bf16x8*)(kB + (size_t)(m1 + (kj >> 4)) * C + (kj & 15) * 8);
                const int vj = tid + rep * 256;
                vpre[rep] = *(const bf16x8*)(vB + (size_t)(vj >> 3) * N + m1 + (vj & 7) * 8);
            }
        }

        // S^T = K Q^T (raw logits)
        floatx4 SA[4], SB[4];
        #pragma unroll
        for (int ct = 0; ct < 4; ++ct) { SA[ct] = fz; SB[ct] = fz; }
        #pragma unroll
        for (int kk = 0; kk < 4; ++kk)
            #pragma unroll
            for (int ct = 0; ct < 4; ++ct) {
                const bf16x8 a = *(bf16x8*)(&k_s[ct * 16 + l15][kk * 32 + quad * 8]);
                SA[ct] = __builtin_amdgcn_mfma_f32_16x16x32_bf16(a, qbA[kk], SA[ct], 0, 0, 0);
                SB[ct] = __builtin_amdgcn_mfma_f32_16x16x32_bf16(a, qbB[kk], SB[ct], 0, 0, 0);
            }

        float rmaxA = -3.0e38f, rmaxB = -3.0e38f;  // raw-domain max (monotonic)
        #pragma unroll
        for (int ct = 0; ct < 4; ++ct)
            #pragma unroll
            for (int r = 0; r < 4; ++r) {
                rmaxA = fmaxf(rmaxA, SA[ct][r]);
                rmaxB = fmaxf(rmaxB, SB[ct][r]);
            }
        rmaxA = fmaxf(rmaxA, __shfl_xor(rmaxA, 16, 64));
        rmaxA = fmaxf(rmaxA, __shfl_xor(rmaxA, 32, 64));
        rmaxB = fmaxf(rmaxB, __shfl_xor(rmaxB, 16, 64));
        rmaxB = fmaxf(rmaxB, __shfl_xor(rmaxB, 32, 64));

        const float mnA = fmaxf(mA, rmaxA);
        const float alphaA = exp2f((mA - mnA) * QSCALE);
        mA = mnA;
        const float mnB = fmaxf(mB, rmaxB);
        const float alphaB = exp2f((mB - mnB) * QSCALE);
        mB = mnB;
        const float qmA = mA * QSCALE, qmB = mB * QSCALE;

        float rsumA = 0.f, rsumB = 0.f;
        #pragma unroll
        for (int ct = 0; ct < 4; ++ct)
            #pragma unroll
            for (int r = 0; r < 4; ++r) {
                const float pA = exp2f(SA[ct][r] * QSCALE - qmA); SA[ct][r] = pA; rsumA += pA;
                const float pB = exp2f(SB[ct][r] * QSCALE - qmB); SB[ct][r] = pB; rsumB += pB;
            }
        rsumA += __shfl_xor(rsumA, 16, 64);
        rsumA += __shfl_xor(rsumA, 32, 64);
        rsumB += __shfl_xor(rsumB, 16, 64);
        rsumB += __shfl_xor(rsumB, 32, 64);
        lA = lA * alphaA + rsumA;
        lB = lB * alphaB + rsumB;

        #pragma unroll
        for (int t = 0; t < 8; ++t)
            #pragma unroll
            for (int r = 0; r < 4; ++r) { OA[t][r] *= alphaA; OB[t][r] *= alphaB; }

        #pragma unroll
        for (int ct = 0; ct < 4; ++ct) {
            bf16x4 pkA, pkB;
            #pragma unroll
            for (int r = 0; r < 4; ++r) { pkA[r] = (__bf16)SA[ct][r]; pkB[r] = (__bf16)SB[ct][r]; }
            *(bf16x4*)(&p_s[wv][l15][ct * 16 + quad * 4])      = pkA;
            *(bf16x4*)(&p_s[wv][16 + l15][ct * 16 + quad * 4]) = pkB;
        }

        #pragma unroll
        for (int kk = 0; kk < 2; ++kk) {
            const bf16x8 pbA = *(bf16x8*)(&p_s[wv][l15][kk * 32 + quad * 8]);
            const bf16x8 pbB = *(bf16x8*)(&p_s[wv][16 + l15][kk * 32 + quad * 8]);
            #pragma unroll
            for (int ct = 0; ct < 8; ++ct) {
                const bf16x8 a = *(bf16x8*)(&v_s[ct * 16 + l15][kk * 32 + quad * 8]);
                OA[ct] = __builtin_amdgcn_mfma_f32_16x16x32_bf16(a, pbA, OA[ct], 0, 0, 0);
                OB[ct] = __builtin_amdgcn_mfma_f32_16x16x32_bf16(a, pbB, OB[ct], 0, 0, 0);
            }
        }
    }

    if (!PARTIAL) {
        const float scA = 1.f / lA, scB = 1.f / lB;
        const float gamma = gamma_p[0];
        #pragma unroll
        for (int ct = 0; ct < 8; ++ct)
            #pragma unroll
            for (int r = 0; r < 4; ++r) {
                const int c = ct * 16 + quad * 4 + r;
                const size_t iA = ((size_t)b * C + c) * N + nA;
                out[iA]      = x[iA]      + gamma * OA[ct][r] * scA;
                out[iA + 16] = x[iA + 16] + gamma * OB[ct][r] * scB;
            }
        return;
    }

    // ---- write partials ----
    __bf16* OpA = Opart + (((size_t)split * Bn + b) * N + nA) * C;
    __bf16* OpB = OpA + (size_t)16 * C;
    #pragma unroll
    for (int ct = 0; ct < 8; ++ct) {
        bf16x4 oA, oB;
        #pragma unroll
        for (int r = 0; r < 4; ++r) { oA[r] = (__bf16)OA[ct][r]; oB[r] = (__bf16)OB[ct][r]; }
        *(bf16x4*)(OpA + ct * 16 + quad * 4) = oA;
        *(bf16x4*)(OpB + ct * 16 + quad * 4) = oB;
    }
    if (quad == 0) {
        float* mlp = ml + (((size_t)split * Bn + b) * N + nA) * 2;
        mlp[0] = mA; mlp[1] = lA;                  // raw-domain m
        mlp[32] = mB; mlp[33] = lB;
    }

    // ---- fused cross-split merge: last-arriving block merges this (b,nt) ----
    __threadfence();                               // release partials (agent scope)
    if (tid == 0) s_old = atomicAdd(&cnt[b * 32 + nt], 1);
    __syncthreads();
    if (s_old != NSPLIT - 1) return;
    __threadfence();                               // acquire others' partials

    const float gamma = gamma_p[0];
    for (int qtr = 0; qtr < 4; ++qtr) {            // 4 x 32-n sub-tiles
        const int nq = n0 + qtr * 32;
        if (tid < 32) {
            const int nn = nq + tid;
            float ms[NSPLIT], ls[NSPLIT];
            #pragma unroll
            for (int s = 0; s < NSPLIT; ++s) {
                const float* mlp = ml + (((size_t)s * Bn + b) * N + nn) * 2;
                ms[s] = mlp[0]; ls[s] = mlp[1];
            }
            float M = -3.0e38f;
            #pragma unroll
            for (int s = 0; s < NSPLIT; ++s) M = fmaxf(M, ms[s]);
            float L = 0.f, e[NSPLIT];
            #pragma unroll
            for (int s = 0; s < NSPLIT; ++s) {
                e[s] = exp2f((ms[s] - M) * QSCALE);
                L += e[s] * ls[s];
            }
            const float inv = 1.f / L;
            #pragma unroll
            for (int s = 0; s < NSPLIT; ++s) cf[s][tid] = e[s] * inv;
        }
        __syncthreads();

        #pragma unroll
        for (int rep = 0; rep < 2; ++rep) {        // 32 n x 16 c-chunks
            const int j = tid + rep * 256;
            const int nl = j >> 4, c8 = (j & 15) * 8;
            float acc[8] = {0, 0, 0, 0, 0, 0, 0, 0};
            #pragma unroll
            for (int s = 0; s < NSPLIT; ++s) {
                const float c0 = cf[s][nl];
                const bf16x8 ov = *(const bf16x8*)(Opart + (((size_t)s * Bn + b) * N + nq + nl) * C + c8);
                #pragma unroll
                for (int t = 0; t < 8; ++t) acc[t] += c0 * (float)ov[t];
            }
            *(float4*)(&ot[nl][c8])     = *(float4*)(&acc[0]);
            *(float4*)(&ot[nl][c8 + 4]) = *(float4*)(&acc[4]);
        }
        __syncthreads();

        const int nl = tid & 31, cbase = tid >> 5;
        #pragma unroll
        for (int k = 0; k < 16; ++k) {
            const int c = cbase * 16 + k;
            const size_t idx = ((size_t)b * C + c) * N + nq + nl;
            out[idx] = x[idx] + gamma * ot[nl][c];
        }
        __syncthreads();
    }
}

extern "C" void kernel_launch(void* const* d_in, const int* in_sizes, int n_in,
                              void* d_out, int out_size, void* d_ws, size_t ws_size,
                              hipStream_t stream) {
    const float* x     = (const float*)d_in[0];
    const float* Wq    = (const float*)d_in[1];
    const float* bq    = (const float*)d_in[2];
    const float* Wk    = (const float*)d_in[3];
    const float* bk    = (const float*)d_in[4];
    const float* Wv    = (const float*)d_in[5];
    const float* bv    = (const float*)d_in[6];
    const float* gamma = (const float*)d_in[7];
    float* out = (float*)d_out;

    constexpr int Bn = 2, C = 128, N = 4096;
    constexpr size_t QKV = (size_t)Bn * N * C;
    __bf16* qT    = (__bf16*)d_ws;
    __bf16* kT    = qT + QKV;
    __bf16* vT2   = kT + QKV;
    __bf16* Opart = vT2 + QKV;
    // layouts for NSPLIT = 8 / 4
    float* ml8 = (float*)(Opart + (size_t)8 * Bn * N * C);
    int*   cnt8 = (int*)(ml8 + (size_t)8 * Bn * N * 2);
    float* ml4 = (float*)(Opart + (size_t)4 * Bn * N * C);
    int*   cnt4 = (int*)(ml4 + (size_t)4 * Bn * N * 2);
    const size_t need8 = (char*)(cnt8 + 64) - (char*)d_ws;
    const size_t need4 = (char*)(cnt4 + 64) - (char*)d_ws;

    proj_kernel<<<dim3(N / 32, 3, Bn), 128, 0, stream>>>(
        x, Wq, bq, Wk, bk, Wv, bv, qT, kT, vT2);

    if (ws_size >= need8) {
        hipMemsetAsync(cnt8, 0, 64 * sizeof(int), stream);
        flash_kernel<8, true><<<32 * 8 * Bn, 256, 0, stream>>>(
            qT, kT, vT2, x, gamma, Opart, ml8, cnt8, out);
    } else if (ws_size >= need4) {
        hipMemsetAsync(cnt4, 0, 64 * sizeof(int), stream);
        flash_kernel<4, true><<<32 * 4 * Bn, 256, 0, stream>>>(
            qT, kT, vT2, x, gamma, Opart, ml4, cnt4, out);
    } else {
        flash_kernel<1, false><<<32 * 1 * Bn, 256, 0, stream>>>(
            qT, kT, vT2, x, gamma, nullptr, nullptr, nullptr, out);
    }
}

// Round 10
// 161.247 us; speedup vs baseline: 1.2945x; 1.2945x over previous
//
#include <hip/hip_runtime.h>
#include <hip/hip_bf16.h>

typedef __bf16 bf16x8 __attribute__((ext_vector_type(8)));
typedef __bf16 bf16x4 __attribute__((ext_vector_type(4)));
typedef float  floatx4 __attribute__((ext_vector_type(4)));

// B=2, C=128, N=4096. fp32 in/out.
// ws: qT[b][n][c] | kT[b][m][c] | vT2[b][c][m] (bf16, 2MB ea)
//     | Opart[s][b][n][c] bf16 | ml[s][b][n][2] f32   (s = NSPLIT)
// Softmax raw-logit domain; 1.3*log2(e) folded into exp2 args via FMA.
// NOTE (R9 lesson): no device-scope fences inside flash — per-XCD L2 invalidation
// thrashed the K/V working set (FETCH +80%). Separate combine kernel instead.

#define QSCALE 1.8755035f   // 1.3 * log2(e)

// ---------------- proj: MFMA QKV, W AND x hi/lo split (3-term) ----------------
// grid (N/32, 3, B), block 128 = 2 waves; wave owns 16 n.  (known-good, R7)
__global__ __launch_bounds__(128) void proj_kernel(
    const float* __restrict__ x,
    const float* __restrict__ Wq, const float* __restrict__ bq,
    const float* __restrict__ Wk, const float* __restrict__ bk,
    const float* __restrict__ Wv, const float* __restrict__ bv,
    __bf16* __restrict__ qT, __bf16* __restrict__ kT, __bf16* __restrict__ vT2)
{
    constexpr int C = 128, N = 4096;
    const int b = blockIdx.z, which = blockIdx.y, n0 = blockIdx.x * 32;
    const int tid = threadIdx.x;
    const int wv = tid >> 6, lane = tid & 63, l15 = lane & 15, quad = lane >> 4;
    const float* W    = (which == 0) ? Wq : (which == 1) ? Wk : Wv;
    const float* bias = (which == 0) ? bq : (which == 1) ? bk : bv;

    __shared__ __bf16 xhi[32][136];
    __shared__ __bf16 xlo[32][136];
    __shared__ __bf16 v_lds[128][40];

    #pragma unroll
    for (int rep = 0; rep < 8; ++rep) {
        const int j = tid + rep * 128;
        const int c = j >> 3, nl4 = (j & 7) * 4;
        const float4 xv = *(const float4*)(x + (size_t)(b * C + c) * N + n0 + nl4);
        #pragma unroll
        for (int r = 0; r < 4; ++r) {
            const float v = (&xv.x)[r];
            const __bf16 h = (__bf16)v;
            xhi[nl4 + r][c] = h;
            xlo[nl4 + r][c] = (__bf16)(v - (float)h);
        }
    }
    __syncthreads();

    bf16x8 xbh[4], xbl[4];
    #pragma unroll
    for (int kk = 0; kk < 4; ++kk) {
        xbh[kk] = *(bf16x8*)(&xhi[wv * 16 + l15][kk * 32 + quad * 8]);
        xbl[kk] = *(bf16x8*)(&xlo[wv * 16 + l15][kk * 32 + quad * 8]);
    }

    floatx4 acc[8];
    const floatx4 fz = {0.f, 0.f, 0.f, 0.f};
    #pragma unroll
    for (int t = 0; t < 8; ++t) acc[t] = fz;

    #pragma unroll
    for (int kk = 0; kk < 4; ++kk)
        #pragma unroll
        for (int ct = 0; ct < 8; ++ct) {
            const float* wp = W + (size_t)(ct * 16 + l15) * C + kk * 32 + quad * 8;
            const float4 w0 = *(const float4*)wp;
            const float4 w1 = *(const float4*)(wp + 4);
            bf16x8 ahi, alo;
            #pragma unroll
            for (int r = 0; r < 4; ++r) {
                const float v0 = (&w0.x)[r]; const __bf16 h0 = (__bf16)v0;
                ahi[r] = h0; alo[r] = (__bf16)(v0 - (float)h0);
                const float v1 = (&w1.x)[r]; const __bf16 h1 = (__bf16)v1;
                ahi[4 + r] = h1; alo[4 + r] = (__bf16)(v1 - (float)h1);
            }
            acc[ct] = __builtin_amdgcn_mfma_f32_16x16x32_bf16(ahi, xbh[kk], acc[ct], 0, 0, 0);
            acc[ct] = __builtin_amdgcn_mfma_f32_16x16x32_bf16(alo, xbh[kk], acc[ct], 0, 0, 0);
            acc[ct] = __builtin_amdgcn_mfma_f32_16x16x32_bf16(ahi, xbl[kk], acc[ct], 0, 0, 0);
        }

    const int n = n0 + wv * 16 + l15;
    if (which < 2) {
        __bf16* dst = (which == 0) ? qT : kT;
        #pragma unroll
        for (int ct = 0; ct < 8; ++ct) {
            const float4 b4 = *(const float4*)(bias + ct * 16 + quad * 4);
            bf16x4 o;
            #pragma unroll
            for (int r = 0; r < 4; ++r) o[r] = (__bf16)(acc[ct][r] + (&b4.x)[r]);
            *(bf16x4*)(dst + (size_t)(b * N + n) * C + ct * 16 + quad * 4) = o;
        }
    } else {
        #pragma unroll
        for (int ct = 0; ct < 8; ++ct) {
            const float4 b4 = *(const float4*)(bias + ct * 16 + quad * 4);
            #pragma unroll
            for (int r = 0; r < 4; ++r)
                v_lds[ct * 16 + quad * 4 + r][wv * 16 + l15] = (__bf16)(acc[ct][r] + (&b4.x)[r]);
        }
        __syncthreads();
        #pragma unroll
        for (int rep = 0; rep < 4; ++rep) {
            const int j = tid + rep * 128;
            const int c = j >> 2, m8 = (j & 3) * 8;
            *(bf16x8*)(vT2 + (size_t)(b * C + c) * N + n0 + m8) = *(bf16x8*)(&v_lds[c][m8]);
        }
    }
}

// ---------------- flash: 128-n tiles, wave owns 32 n (2 B-fragments) ----------------
// block 256 = 4 waves. LDS = 54272 B -> 3 blocks/CU co-resident (162816 <= 163840).
// grid flat 32*NSPLIT*B, XCD-pinned on batch via bid&7 (K+V per batch = 2MB, L2-resident).
template <int NSPLIT, bool PARTIAL>
__global__ __launch_bounds__(256, 3) void flash_kernel(
    const __bf16* __restrict__ qT, const __bf16* __restrict__ kT,
    const __bf16* __restrict__ vT2, const float* __restrict__ x,
    const float* __restrict__ gamma_p, __bf16* __restrict__ Opart,
    float* __restrict__ ml, float* __restrict__ out)
{
    constexpr int C = 128, N = 4096, Bn = 2;
    const int bid = blockIdx.x;
    const int r7 = bid & 7;
    const int b = r7 >> 2;                         // XCD-pinned batch
    const int rest = (bid >> 3) * 4 + (r7 & 3);    // 0 .. 32*NSPLIT-1
    const int nt = rest / NSPLIT, split = rest % NSPLIT;
    const int n0 = nt * 128;
    const int tid = threadIdx.x;
    const int wv = tid >> 6, lane = tid & 63, l15 = lane & 15, quad = lane >> 4;

    __shared__ __bf16 k_s[64][136];
    __shared__ __bf16 v_s[128][72];
    __shared__ __bf16 p_s[4][32][72];

    const int nA = n0 + wv * 32 + l15;             // col set A; B = +16
    bf16x8 qbA[4], qbB[4];
    #pragma unroll
    for (int kk = 0; kk < 4; ++kk) {
        qbA[kk] = *(const bf16x8*)(qT + (size_t)(b * N + nA) * C + kk * 32 + quad * 8);
        qbB[kk] = *(const bf16x8*)(qT + (size_t)(b * N + nA + 16) * C + kk * 32 + quad * 8);
    }

    float mA = -3.0e38f, lA = 0.f, mB = -3.0e38f, lB = 0.f;  // raw-logit domain
    floatx4 OA[8], OB[8];
    const floatx4 fz = {0.f, 0.f, 0.f, 0.f};
    #pragma unroll
    for (int t = 0; t < 8; ++t) { OA[t] = fz; OB[t] = fz; }

    const __bf16* kB = kT  + (size_t)b * N * C;
    const __bf16* vB = vT2 + (size_t)b * C * N;
    constexpr int ITERS = (N / NSPLIT) / 64;
    const int mbeg = split * (N / NSPLIT);

    bf16x8 kpre[4], vpre[4];
    #pragma unroll
    for (int rep = 0; rep < 4; ++rep) {
        const int kj = tid + rep * 256;
        kpre[rep] = *(const bf16x8*)(kB + (size_t)(mbeg + (kj >> 4)) * C + (kj & 15) * 8);
        const int vj = tid + rep * 256;
        vpre[rep] = *(const bf16x8*)(vB + (size_t)(vj >> 3) * N + mbeg + (vj & 7) * 8);
    }

    for (int it = 0; it < ITERS; ++it) {
        __syncthreads();
        #pragma unroll
        for (int rep = 0; rep < 4; ++rep) {
            const int kj = tid + rep * 256;
            *(bf16x8*)(&k_s[kj >> 4][(kj & 15) * 8]) = kpre[rep];
            const int vj = tid + rep * 256;
            *(bf16x8*)(&v_s[vj >> 3][(vj & 7) * 8]) = vpre[rep];
        }
        __syncthreads();

        if (it + 1 < ITERS) {
            const int m1 = mbeg + (it + 1) * 64;
            #pragma unroll
            for (int rep = 0; rep < 4; ++rep) {
                const int kj = tid + rep * 256;
                kpre[rep] = *(const bf16x8*)(kB + (size_t)(m1 + (kj >> 4)) * C + (kj & 15) * 8);
                const int vj = tid + rep * 256;
                vpre[rep] = *(const bf16x8*)(vB + (size_t)(vj >> 3) * N + m1 + (vj & 7) * 8);
            }
        }

        // S^T = K Q^T (raw logits)
        floatx4 SA[4], SB[4];
        #pragma unroll
        for (int ct = 0; ct < 4; ++ct) { SA[ct] = fz; SB[ct] = fz; }
        #pragma unroll
        for (int kk = 0; kk < 4; ++kk)
            #pragma unroll
            for (int ct = 0; ct < 4; ++ct) {
                const bf16x8 a = *(bf16x8*)(&k_s[ct * 16 + l15][kk * 32 + quad * 8]);
                SA[ct] = __builtin_amdgcn_mfma_f32_16x16x32_bf16(a, qbA[kk], SA[ct], 0, 0, 0);
                SB[ct] = __builtin_amdgcn_mfma_f32_16x16x32_bf16(a, qbB[kk], SB[ct], 0, 0, 0);
            }

        float rmaxA = -3.0e38f, rmaxB = -3.0e38f;
        #pragma unroll
        for (int ct = 0; ct < 4; ++ct)
            #pragma unroll
            for (int r = 0; r < 4; ++r) {
                rmaxA = fmaxf(rmaxA, SA[ct][r]);
                rmaxB = fmaxf(rmaxB, SB[ct][r]);
            }
        rmaxA = fmaxf(rmaxA, __shfl_xor(rmaxA, 16, 64));
        rmaxA = fmaxf(rmaxA, __shfl_xor(rmaxA, 32, 64));
        rmaxB = fmaxf(rmaxB, __shfl_xor(rmaxB, 16, 64));
        rmaxB = fmaxf(rmaxB, __shfl_xor(rmaxB, 32, 64));

        // wave-uniform alpha-skip: only rescale when some lane's max grew
        const bool up = (rmaxA > mA) || (rmaxB > mB);
        if (__any(up)) {
            const float mnA = fmaxf(mA, rmaxA);
            const float mnB = fmaxf(mB, rmaxB);
            const float alphaA = exp2f((mA - mnA) * QSCALE);
            const float alphaB = exp2f((mB - mnB) * QSCALE);
            mA = mnA; mB = mnB;
            lA *= alphaA; lB *= alphaB;
            #pragma unroll
            for (int t = 0; t < 8; ++t)
                #pragma unroll
                for (int r = 0; r < 4; ++r) { OA[t][r] *= alphaA; OB[t][r] *= alphaB; }
        }
        const float qmA = mA * QSCALE, qmB = mB * QSCALE;

        float rsumA = 0.f, rsumB = 0.f;
        #pragma unroll
        for (int ct = 0; ct < 4; ++ct)
            #pragma unroll
            for (int r = 0; r < 4; ++r) {
                const float pA = exp2f(SA[ct][r] * QSCALE - qmA); SA[ct][r] = pA; rsumA += pA;
                const float pB = exp2f(SB[ct][r] * QSCALE - qmB); SB[ct][r] = pB; rsumB += pB;
            }
        rsumA += __shfl_xor(rsumA, 16, 64);
        rsumA += __shfl_xor(rsumA, 32, 64);
        rsumB += __shfl_xor(rsumB, 16, 64);
        rsumB += __shfl_xor(rsumB, 32, 64);
        lA += rsumA;
        lB += rsumB;

        #pragma unroll
        for (int ct = 0; ct < 4; ++ct) {
            bf16x4 pkA, pkB;
            #pragma unroll
            for (int r = 0; r < 4; ++r) { pkA[r] = (__bf16)SA[ct][r]; pkB[r] = (__bf16)SB[ct][r]; }
            *(bf16x4*)(&p_s[wv][l15][ct * 16 + quad * 4])      = pkA;
            *(bf16x4*)(&p_s[wv][16 + l15][ct * 16 + quad * 4]) = pkB;
        }

        #pragma unroll
        for (int kk = 0; kk < 2; ++kk) {
            const bf16x8 pbA = *(bf16x8*)(&p_s[wv][l15][kk * 32 + quad * 8]);
            const bf16x8 pbB = *(bf16x8*)(&p_s[wv][16 + l15][kk * 32 + quad * 8]);
            #pragma unroll
            for (int ct = 0; ct < 8; ++ct) {
                const bf16x8 a = *(bf16x8*)(&v_s[ct * 16 + l15][kk * 32 + quad * 8]);
                OA[ct] = __builtin_amdgcn_mfma_f32_16x16x32_bf16(a, pbA, OA[ct], 0, 0, 0);
                OB[ct] = __builtin_amdgcn_mfma_f32_16x16x32_bf16(a, pbB, OB[ct], 0, 0, 0);
            }
        }
    }

    if (PARTIAL) {
        __bf16* OpA = Opart + (((size_t)split * Bn + b) * N + nA) * C;
        __bf16* OpB = OpA + (size_t)16 * C;
        #pragma unroll
        for (int ct = 0; ct < 8; ++ct) {
            bf16x4 oA, oB;
            #pragma unroll
            for (int r = 0; r < 4; ++r) { oA[r] = (__bf16)OA[ct][r]; oB[r] = (__bf16)OB[ct][r]; }
            *(bf16x4*)(OpA + ct * 16 + quad * 4) = oA;
            *(bf16x4*)(OpB + ct * 16 + quad * 4) = oB;
        }
        if (quad == 0) {
            float* mlp = ml + (((size_t)split * Bn + b) * N + nA) * 2;
            mlp[0] = mA; mlp[1] = lA;              // raw-domain m
            mlp[32] = mB; mlp[33] = lB;
        }
    } else {
        const float scA = 1.f / lA, scB = 1.f / lB;
        const float gamma = gamma_p[0];
        #pragma unroll
        for (int ct = 0; ct < 8; ++ct)
            #pragma unroll
            for (int r = 0; r < 4; ++r) {
                const int c = ct * 16 + quad * 4 + r;
                const size_t iA = ((size_t)b * C + c) * N + nA;
                out[iA]      = x[iA]      + gamma * OA[ct][r] * scA;
                out[iA + 16] = x[iA + 16] + gamma * OB[ct][r] * scB;
            }
    }
}

// ---------------- combine: merge S splits + epilogue ----------------
// grid (N/16, B), block 128 (16-n tiles -> 512 blocks, latency-hidden).
template <int S>
__global__ __launch_bounds__(128) void combine_kernel(
    const __bf16* __restrict__ Opart, const float* __restrict__ ml,
    const float* __restrict__ x, const float* __restrict__ gamma_p,
    float* __restrict__ out)
{
    constexpr int C = 128, N = 4096, Bn = 2;
    const int b = blockIdx.y, n0 = blockIdx.x * 16;
    const int tid = threadIdx.x;
    __shared__ float cf[S][16];
    __shared__ float ot[16][132];

    if (tid < 16) {
        const int n = n0 + tid;
        float ms[S], ls[S];
        #pragma unroll
        for (int s = 0; s < S; ++s) {
            const float* mlp = ml + (((size_t)s * Bn + b) * N + n) * 2;
            ms[s] = mlp[0]; ls[s] = mlp[1];
        }
        float M = -3.0e38f;
        #pragma unroll
        for (int s = 0; s < S; ++s) M = fmaxf(M, ms[s]);
        float L = 0.f, e[S];
        #pragma unroll
        for (int s = 0; s < S; ++s) { e[s] = exp2f((ms[s] - M) * QSCALE); L += e[s] * ls[s]; }
        const float inv = 1.f / L;
        #pragma unroll
        for (int s = 0; s < S; ++s) cf[s][tid] = e[s] * inv;
    }
    __syncthreads();

    #pragma unroll
    for (int rep = 0; rep < 2; ++rep) {            // 16 n x 16 c-chunks
        const int j = tid + rep * 128;
        const int nl = j >> 4, c8 = (j & 15) * 8;
        float acc[8] = {0, 0, 0, 0, 0, 0, 0, 0};
        #pragma unroll
        for (int s = 0; s < S; ++s) {
            const float c0 = cf[s][nl];
            const bf16x8 ov = *(const bf16x8*)(Opart + (((size_t)s * Bn + b) * N + n0 + nl) * C + c8);
            #pragma unroll
            for (int t = 0; t < 8; ++t) acc[t] += c0 * (float)ov[t];
        }
        *(float4*)(&ot[nl][c8])     = *(float4*)(&acc[0]);
        *(float4*)(&ot[nl][c8 + 4]) = *(float4*)(&acc[4]);
    }
    __syncthreads();

    const int nl = tid & 15, cbase = tid >> 4;     // 8 c-groups x 16 c
    const float gamma = gamma_p[0];
    #pragma unroll
    for (int k = 0; k < 16; ++k) {
        const int c = cbase * 16 + k;
        const size_t idx = ((size_t)b * C + c) * N + n0 + nl;
        out[idx] = x[idx] + gamma * ot[nl][c];
    }
}

extern "C" void kernel_launch(void* const* d_in, const int* in_sizes, int n_in,
                              void* d_out, int out_size, void* d_ws, size_t ws_size,
                              hipStream_t stream) {
    const float* x     = (const float*)d_in[0];
    const float* Wq    = (const float*)d_in[1];
    const float* bq    = (const float*)d_in[2];
    const float* Wk    = (const float*)d_in[3];
    const float* bk    = (const float*)d_in[4];
    const float* Wv    = (const float*)d_in[5];
    const float* bv    = (const float*)d_in[6];
    const float* gamma = (const float*)d_in[7];
    float* out = (float*)d_out;

    constexpr int Bn = 2, C = 128, N = 4096;
    constexpr size_t QKV = (size_t)Bn * N * C;
    __bf16* qT    = (__bf16*)d_ws;
    __bf16* kT    = qT + QKV;
    __bf16* vT2   = kT + QKV;
    __bf16* Opart = vT2 + QKV;
    float* ml8 = (float*)(Opart + (size_t)8 * Bn * N * C);
    float* ml4 = (float*)(Opart + (size_t)4 * Bn * N * C);
    const size_t need8 = (char*)(ml8 + (size_t)8 * Bn * N * 2) - (char*)d_ws;
    const size_t need4 = (char*)(ml4 + (size_t)4 * Bn * N * 2) - (char*)d_ws;

    proj_kernel<<<dim3(N / 32, 3, Bn), 128, 0, stream>>>(
        x, Wq, bq, Wk, bk, Wv, bv, qT, kT, vT2);

    if (ws_size >= need8) {
        flash_kernel<8, true><<<32 * 8 * Bn, 256, 0, stream>>>(
            qT, kT, vT2, x, gamma, Opart, ml8, out);
        combine_kernel<8><<<dim3(N / 16, Bn), 128, 0, stream>>>(
            Opart, ml8, x, gamma, out);
    } else if (ws_size >= need4) {
        flash_kernel<4, true><<<32 * 4 * Bn, 256, 0, stream>>>(
            qT, kT, vT2, x, gamma, Opart, ml4, out);
        combine_kernel<4><<<dim3(N / 16, Bn), 128, 0, stream>>>(
            Opart, ml4, x, gamma, out);
    } else {
        flash_kernel<1, false><<<32 * 1 * Bn, 256, 0, stream>>>(
            qT, kT, vT2, x, gamma, nullptr, nullptr, out);
    }
}

// Round 11
// 122.300 us; speedup vs baseline: 1.7067x; 1.3185x over previous
//
#include <hip/hip_runtime.h>
#include <hip/hip_bf16.h>

typedef __bf16 bf16x8 __attribute__((ext_vector_type(8)));
typedef __bf16 bf16x4 __attribute__((ext_vector_type(4)));
typedef float  floatx4 __attribute__((ext_vector_type(4)));

// B=2, C=128, N=4096. fp32 in/out.
// ws: qT[b][n][c] | kT[b][m][c] | vT2[b][c][m] (bf16, 2MB ea)
//     | Opart[s][b][n][c] bf16 | ml[s][b][n][2] f32   (s = NSPLIT)
// Softmax raw-logit domain; 1.3*log2(e) folded into exp2 args via FMA.
// R9 lesson: no device-scope fences in flash (L2 invalidation thrash).
// R10 lesson: no __launch_bounds__(256,3) — caps VGPR at 170 < ~200 live set
//   -> 135 MB scratch spill. (256,2) allocates ~120 VGPR, zero spill; LDS
//   (54272*3 <= 163840) already permits 3 blocks/CU.

#define QSCALE 1.8755035f   // 1.3 * log2(e)

// ---------------- proj: MFMA QKV, W AND x hi/lo split (3-term) ----------------
// grid (N/32, 3, B), block 128 = 2 waves; wave owns 16 n.  (known-good, R7)
__global__ __launch_bounds__(128) void proj_kernel(
    const float* __restrict__ x,
    const float* __restrict__ Wq, const float* __restrict__ bq,
    const float* __restrict__ Wk, const float* __restrict__ bk,
    const float* __restrict__ Wv, const float* __restrict__ bv,
    __bf16* __restrict__ qT, __bf16* __restrict__ kT, __bf16* __restrict__ vT2)
{
    constexpr int C = 128, N = 4096;
    const int b = blockIdx.z, which = blockIdx.y, n0 = blockIdx.x * 32;
    const int tid = threadIdx.x;
    const int wv = tid >> 6, lane = tid & 63, l15 = lane & 15, quad = lane >> 4;
    const float* W    = (which == 0) ? Wq : (which == 1) ? Wk : Wv;
    const float* bias = (which == 0) ? bq : (which == 1) ? bk : bv;

    __shared__ __bf16 xhi[32][136];
    __shared__ __bf16 xlo[32][136];
    __shared__ __bf16 v_lds[128][40];

    #pragma unroll
    for (int rep = 0; rep < 8; ++rep) {
        const int j = tid + rep * 128;
        const int c = j >> 3, nl4 = (j & 7) * 4;
        const float4 xv = *(const float4*)(x + (size_t)(b * C + c) * N + n0 + nl4);
        #pragma unroll
        for (int r = 0; r < 4; ++r) {
            const float v = (&xv.x)[r];
            const __bf16 h = (__bf16)v;
            xhi[nl4 + r][c] = h;
            xlo[nl4 + r][c] = (__bf16)(v - (float)h);
        }
    }
    __syncthreads();

    bf16x8 xbh[4], xbl[4];
    #pragma unroll
    for (int kk = 0; kk < 4; ++kk) {
        xbh[kk] = *(bf16x8*)(&xhi[wv * 16 + l15][kk * 32 + quad * 8]);
        xbl[kk] = *(bf16x8*)(&xlo[wv * 16 + l15][kk * 32 + quad * 8]);
    }

    floatx4 acc[8];
    const floatx4 fz = {0.f, 0.f, 0.f, 0.f};
    #pragma unroll
    for (int t = 0; t < 8; ++t) acc[t] = fz;

    #pragma unroll
    for (int kk = 0; kk < 4; ++kk)
        #pragma unroll
        for (int ct = 0; ct < 8; ++ct) {
            const float* wp = W + (size_t)(ct * 16 + l15) * C + kk * 32 + quad * 8;
            const float4 w0 = *(const float4*)wp;
            const float4 w1 = *(const float4*)(wp + 4);
            bf16x8 ahi, alo;
            #pragma unroll
            for (int r = 0; r < 4; ++r) {
                const float v0 = (&w0.x)[r]; const __bf16 h0 = (__bf16)v0;
                ahi[r] = h0; alo[r] = (__bf16)(v0 - (float)h0);
                const float v1 = (&w1.x)[r]; const __bf16 h1 = (__bf16)v1;
                ahi[4 + r] = h1; alo[4 + r] = (__bf16)(v1 - (float)h1);
            }
            acc[ct] = __builtin_amdgcn_mfma_f32_16x16x32_bf16(ahi, xbh[kk], acc[ct], 0, 0, 0);
            acc[ct] = __builtin_amdgcn_mfma_f32_16x16x32_bf16(alo, xbh[kk], acc[ct], 0, 0, 0);
            acc[ct] = __builtin_amdgcn_mfma_f32_16x16x32_bf16(ahi, xbl[kk], acc[ct], 0, 0, 0);
        }

    const int n = n0 + wv * 16 + l15;
    if (which < 2) {
        __bf16* dst = (which == 0) ? qT : kT;
        #pragma unroll
        for (int ct = 0; ct < 8; ++ct) {
            const float4 b4 = *(const float4*)(bias + ct * 16 + quad * 4);
            bf16x4 o;
            #pragma unroll
            for (int r = 0; r < 4; ++r) o[r] = (__bf16)(acc[ct][r] + (&b4.x)[r]);
            *(bf16x4*)(dst + (size_t)(b * N + n) * C + ct * 16 + quad * 4) = o;
        }
    } else {
        #pragma unroll
        for (int ct = 0; ct < 8; ++ct) {
            const float4 b4 = *(const float4*)(bias + ct * 16 + quad * 4);
            #pragma unroll
            for (int r = 0; r < 4; ++r)
                v_lds[ct * 16 + quad * 4 + r][wv * 16 + l15] = (__bf16)(acc[ct][r] + (&b4.x)[r]);
        }
        __syncthreads();
        #pragma unroll
        for (int rep = 0; rep < 4; ++rep) {
            const int j = tid + rep * 128;
            const int c = j >> 2, m8 = (j & 3) * 8;
            *(bf16x8*)(vT2 + (size_t)(b * C + c) * N + n0 + m8) = *(bf16x8*)(&v_lds[c][m8]);
        }
    }
}

// ---------------- flash: 128-n tiles, wave owns 32 n (2 B-fragments) ----------------
// block 256 = 4 waves. LDS = 54272 B -> 3 blocks/CU (LDS-limited; VGPR ~120 @ (256,2)).
// grid flat 32*NSPLIT*B, XCD-pinned on batch via bid&7 (K+V per batch = 2MB, L2-resident).
template <int NSPLIT, bool PARTIAL>
__global__ __launch_bounds__(256, 2) void flash_kernel(
    const __bf16* __restrict__ qT, const __bf16* __restrict__ kT,
    const __bf16* __restrict__ vT2, const float* __restrict__ x,
    const float* __restrict__ gamma_p, __bf16* __restrict__ Opart,
    float* __restrict__ ml, float* __restrict__ out)
{
    constexpr int C = 128, N = 4096, Bn = 2;
    const int bid = blockIdx.x;
    const int r7 = bid & 7;
    const int b = r7 >> 2;                         // XCD-pinned batch
    const int rest = (bid >> 3) * 4 + (r7 & 3);    // 0 .. 32*NSPLIT-1
    const int nt = rest / NSPLIT, split = rest % NSPLIT;
    const int n0 = nt * 128;
    const int tid = threadIdx.x;
    const int wv = tid >> 6, lane = tid & 63, l15 = lane & 15, quad = lane >> 4;

    __shared__ __bf16 k_s[64][136];
    __shared__ __bf16 v_s[128][72];
    __shared__ __bf16 p_s[4][32][72];

    const int nA = n0 + wv * 32 + l15;             // col set A; B = +16
    bf16x8 qbA[4], qbB[4];
    #pragma unroll
    for (int kk = 0; kk < 4; ++kk) {
        qbA[kk] = *(const bf16x8*)(qT + (size_t)(b * N + nA) * C + kk * 32 + quad * 8);
        qbB[kk] = *(const bf16x8*)(qT + (size_t)(b * N + nA + 16) * C + kk * 32 + quad * 8);
    }

    float mA = -3.0e38f, lA = 0.f, mB = -3.0e38f, lB = 0.f;  // raw-logit domain
    floatx4 OA[8], OB[8];
    const floatx4 fz = {0.f, 0.f, 0.f, 0.f};
    #pragma unroll
    for (int t = 0; t < 8; ++t) { OA[t] = fz; OB[t] = fz; }

    const __bf16* kB = kT  + (size_t)b * N * C;
    const __bf16* vB = vT2 + (size_t)b * C * N;
    constexpr int ITERS = (N / NSPLIT) / 64;
    const int mbeg = split * (N / NSPLIT);

    bf16x8 kpre[4], vpre[4];
    #pragma unroll
    for (int rep = 0; rep < 4; ++rep) {
        const int kj = tid + rep * 256;
        kpre[rep] = *(const bf16x8*)(kB + (size_t)(mbeg + (kj >> 4)) * C + (kj & 15) * 8);
        const int vj = tid + rep * 256;
        vpre[rep] = *(const bf16x8*)(vB + (size_t)(vj >> 3) * N + mbeg + (vj & 7) * 8);
    }

    for (int it = 0; it < ITERS; ++it) {
        __syncthreads();
        #pragma unroll
        for (int rep = 0; rep < 4; ++rep) {
            const int kj = tid + rep * 256;
            *(bf16x8*)(&k_s[kj >> 4][(kj & 15) * 8]) = kpre[rep];
            const int vj = tid + rep * 256;
            *(bf16x8*)(&v_s[vj >> 3][(vj & 7) * 8]) = vpre[rep];
        }
        __syncthreads();

        if (it + 1 < ITERS) {
            const int m1 = mbeg + (it + 1) * 64;
            #pragma unroll
            for (int rep = 0; rep < 4; ++rep) {
                const int kj = tid + rep * 256;
                kpre[rep] = *(const bf16x8*)(kB + (size_t)(m1 + (kj >> 4)) * C + (kj & 15) * 8);
                const int vj = tid + rep * 256;
                vpre[rep] = *(const bf16x8*)(vB + (size_t)(vj >> 3) * N + m1 + (vj & 7) * 8);
            }
        }

        // S^T = K Q^T (raw logits)
        floatx4 SA[4], SB[4];
        #pragma unroll
        for (int ct = 0; ct < 4; ++ct) { SA[ct] = fz; SB[ct] = fz; }
        #pragma unroll
        for (int kk = 0; kk < 4; ++kk)
            #pragma unroll
            for (int ct = 0; ct < 4; ++ct) {
                const bf16x8 a = *(bf16x8*)(&k_s[ct * 16 + l15][kk * 32 + quad * 8]);
                SA[ct] = __builtin_amdgcn_mfma_f32_16x16x32_bf16(a, qbA[kk], SA[ct], 0, 0, 0);
                SB[ct] = __builtin_amdgcn_mfma_f32_16x16x32_bf16(a, qbB[kk], SB[ct], 0, 0, 0);
            }

        float rmaxA = -3.0e38f, rmaxB = -3.0e38f;
        #pragma unroll
        for (int ct = 0; ct < 4; ++ct)
            #pragma unroll
            for (int r = 0; r < 4; ++r) {
                rmaxA = fmaxf(rmaxA, SA[ct][r]);
                rmaxB = fmaxf(rmaxB, SB[ct][r]);
            }
        rmaxA = fmaxf(rmaxA, __shfl_xor(rmaxA, 16, 64));
        rmaxA = fmaxf(rmaxA, __shfl_xor(rmaxA, 32, 64));
        rmaxB = fmaxf(rmaxB, __shfl_xor(rmaxB, 16, 64));
        rmaxB = fmaxf(rmaxB, __shfl_xor(rmaxB, 32, 64));

        const float mnA = fmaxf(mA, rmaxA);
        const float alphaA = exp2f((mA - mnA) * QSCALE);
        mA = mnA;
        const float mnB = fmaxf(mB, rmaxB);
        const float alphaB = exp2f((mB - mnB) * QSCALE);
        mB = mnB;
        const float qmA = mA * QSCALE, qmB = mB * QSCALE;

        float rsumA = 0.f, rsumB = 0.f;
        #pragma unroll
        for (int ct = 0; ct < 4; ++ct)
            #pragma unroll
            for (int r = 0; r < 4; ++r) {
                const float pA = exp2f(SA[ct][r] * QSCALE - qmA); SA[ct][r] = pA; rsumA += pA;
                const float pB = exp2f(SB[ct][r] * QSCALE - qmB); SB[ct][r] = pB; rsumB += pB;
            }
        rsumA += __shfl_xor(rsumA, 16, 64);
        rsumA += __shfl_xor(rsumA, 32, 64);
        rsumB += __shfl_xor(rsumB, 16, 64);
        rsumB += __shfl_xor(rsumB, 32, 64);
        lA = lA * alphaA + rsumA;
        lB = lB * alphaB + rsumB;

        #pragma unroll
        for (int t = 0; t < 8; ++t)
            #pragma unroll
            for (int r = 0; r < 4; ++r) { OA[t][r] *= alphaA; OB[t][r] *= alphaB; }

        #pragma unroll
        for (int ct = 0; ct < 4; ++ct) {
            bf16x4 pkA, pkB;
            #pragma unroll
            for (int r = 0; r < 4; ++r) { pkA[r] = (__bf16)SA[ct][r]; pkB[r] = (__bf16)SB[ct][r]; }
            *(bf16x4*)(&p_s[wv][l15][ct * 16 + quad * 4])      = pkA;
            *(bf16x4*)(&p_s[wv][16 + l15][ct * 16 + quad * 4]) = pkB;
        }

        #pragma unroll
        for (int kk = 0; kk < 2; ++kk) {
            const bf16x8 pbA = *(bf16x8*)(&p_s[wv][l15][kk * 32 + quad * 8]);
            const bf16x8 pbB = *(bf16x8*)(&p_s[wv][16 + l15][kk * 32 + quad * 8]);
            #pragma unroll
            for (int ct = 0; ct < 8; ++ct) {
                const bf16x8 a = *(bf16x8*)(&v_s[ct * 16 + l15][kk * 32 + quad * 8]);
                OA[ct] = __builtin_amdgcn_mfma_f32_16x16x32_bf16(a, pbA, OA[ct], 0, 0, 0);
                OB[ct] = __builtin_amdgcn_mfma_f32_16x16x32_bf16(a, pbB, OB[ct], 0, 0, 0);
            }
        }
    }

    if (PARTIAL) {
        __bf16* OpA = Opart + (((size_t)split * Bn + b) * N + nA) * C;
        __bf16* OpB = OpA + (size_t)16 * C;
        #pragma unroll
        for (int ct = 0; ct < 8; ++ct) {
            bf16x4 oA, oB;
            #pragma unroll
            for (int r = 0; r < 4; ++r) { oA[r] = (__bf16)OA[ct][r]; oB[r] = (__bf16)OB[ct][r]; }
            *(bf16x4*)(OpA + ct * 16 + quad * 4) = oA;
            *(bf16x4*)(OpB + ct * 16 + quad * 4) = oB;
        }
        if (quad == 0) {
            float* mlp = ml + (((size_t)split * Bn + b) * N + nA) * 2;
            mlp[0] = mA; mlp[1] = lA;              // raw-domain m
            mlp[32] = mB; mlp[33] = lB;
        }
    } else {
        const float scA = 1.f / lA, scB = 1.f / lB;
        const float gamma = gamma_p[0];
        #pragma unroll
        for (int ct = 0; ct < 8; ++ct)
            #pragma unroll
            for (int r = 0; r < 4; ++r) {
                const int c = ct * 16 + quad * 4 + r;
                const size_t iA = ((size_t)b * C + c) * N + nA;
                out[iA]      = x[iA]      + gamma * OA[ct][r] * scA;
                out[iA + 16] = x[iA + 16] + gamma * OB[ct][r] * scB;
            }
    }
}

// ---------------- combine: merge S splits + epilogue ----------------
// grid (N/16, B), block 128 (16-n tiles -> 512 blocks, latency-hidden).
template <int S>
__global__ __launch_bounds__(128) void combine_kernel(
    const __bf16* __restrict__ Opart, const float* __restrict__ ml,
    const float* __restrict__ x, const float* __restrict__ gamma_p,
    float* __restrict__ out)
{
    constexpr int C = 128, N = 4096, Bn = 2;
    const int b = blockIdx.y, n0 = blockIdx.x * 16;
    const int tid = threadIdx.x;
    __shared__ float cf[S][16];
    __shared__ float ot[16][132];

    if (tid < 16) {
        const int n = n0 + tid;
        float ms[S], ls[S];
        #pragma unroll
        for (int s = 0; s < S; ++s) {
            const float* mlp = ml + (((size_t)s * Bn + b) * N + n) * 2;
            ms[s] = mlp[0]; ls[s] = mlp[1];
        }
        float M = -3.0e38f;
        #pragma unroll
        for (int s = 0; s < S; ++s) M = fmaxf(M, ms[s]);
        float L = 0.f, e[S];
        #pragma unroll
        for (int s = 0; s < S; ++s) { e[s] = exp2f((ms[s] - M) * QSCALE); L += e[s] * ls[s]; }
        const float inv = 1.f / L;
        #pragma unroll
        for (int s = 0; s < S; ++s) cf[s][tid] = e[s] * inv;
    }
    __syncthreads();

    #pragma unroll
    for (int rep = 0; rep < 2; ++rep) {            // 16 n x 16 c-chunks
        const int j = tid + rep * 128;
        const int nl = j >> 4, c8 = (j & 15) * 8;
        float acc[8] = {0, 0, 0, 0, 0, 0, 0, 0};
        #pragma unroll
        for (int s = 0; s < S; ++s) {
            const float c0 = cf[s][nl];
            const bf16x8 ov = *(const bf16x8*)(Opart + (((size_t)s * Bn + b) * N + n0 + nl) * C + c8);
            #pragma unroll
            for (int t = 0; t < 8; ++t) acc[t] += c0 * (float)ov[t];
        }
        *(float4*)(&ot[nl][c8])     = *(float4*)(&acc[0]);
        *(float4*)(&ot[nl][c8 + 4]) = *(float4*)(&acc[4]);
    }
    __syncthreads();

    const int nl = tid & 15, cbase = tid >> 4;     // 8 c-groups x 16 c
    const float gamma = gamma_p[0];
    #pragma unroll
    for (int k = 0; k < 16; ++k) {
        const int c = cbase * 16 + k;
        const size_t idx = ((size_t)b * C + c) * N + n0 + nl;
        out[idx] = x[idx] + gamma * ot[nl][c];
    }
}

extern "C" void kernel_launch(void* const* d_in, const int* in_sizes, int n_in,
                              void* d_out, int out_size, void* d_ws, size_t ws_size,
                              hipStream_t stream) {
    const float* x     = (const float*)d_in[0];
    const float* Wq    = (const float*)d_in[1];
    const float* bq    = (const float*)d_in[2];
    const float* Wk    = (const float*)d_in[3];
    const float* bk    = (const float*)d_in[4];
    const float* Wv    = (const float*)d_in[5];
    const float* bv    = (const float*)d_in[6];
    const float* gamma = (const float*)d_in[7];
    float* out = (float*)d_out;

    constexpr int Bn = 2, C = 128, N = 4096;
    constexpr size_t QKV = (size_t)Bn * N * C;
    __bf16* qT    = (__bf16*)d_ws;
    __bf16* kT    = qT + QKV;
    __bf16* vT2   = kT + QKV;
    __bf16* Opart = vT2 + QKV;
    float* ml8 = (float*)(Opart + (size_t)8 * Bn * N * C);
    float* ml4 = (float*)(Opart + (size_t)4 * Bn * N * C);
    const size_t need8 = (char*)(ml8 + (size_t)8 * Bn * N * 2) - (char*)d_ws;
    const size_t need4 = (char*)(ml4 + (size_t)4 * Bn * N * 2) - (char*)d_ws;

    proj_kernel<<<dim3(N / 32, 3, Bn), 128, 0, stream>>>(
        x, Wq, bq, Wk, bk, Wv, bv, qT, kT, vT2);

    if (ws_size >= need8) {
        flash_kernel<8, true><<<32 * 8 * Bn, 256, 0, stream>>>(
            qT, kT, vT2, x, gamma, Opart, ml8, out);
        combine_kernel<8><<<dim3(N / 16, Bn), 128, 0, stream>>>(
            Opart, ml8, x, gamma, out);
    } else if (ws_size >= need4) {
        flash_kernel<4, true><<<32 * 4 * Bn, 256, 0, stream>>>(
            qT, kT, vT2, x, gamma, Opart, ml4, out);
        combine_kernel<4><<<dim3(N / 16, Bn), 128, 0, stream>>>(
            Opart, ml4, x, gamma, out);
    } else {
        flash_kernel<1, false><<<32 * 1 * Bn, 256, 0, stream>>>(
            qT, kT, vT2, x, gamma, nullptr, nullptr, out);
    }
}